// Round 2
// baseline (177.403 us; speedup 1.0000x reference)
//
#include <hip/hip_runtime.h>

// One 64-lane wave per game. Each lane owns 4 consecutive cells of the
// 256-cell board (int4 load / int4 store). Game-level logic is
// wave-uniform; cross-cell fetches use __shfl. rand_food is only read for
// the ~0.4% of games that spawn food (wave-uniform branch).
// NOTE: harness reads d_out as int32 (reference output dtype is integer).
__global__ __launch_bounds__(256) void snake_step(
    const int*   __restrict__ action,
    const int*   __restrict__ pos_prev,
    const int*   __restrict__ pos_cur,
    const int*   __restrict__ state,
    const float* __restrict__ rand_food,
    int*         __restrict__ out,
    int G)
{
    const int lane = threadIdx.x & 63;
    const int wv   = threadIdx.x >> 6;
    const int g    = blockIdx.x * 4 + wv;
    if (g >= G) return;

    // Load this lane's 4 cells (int8 in reference, delivered as int32).
    const int4 cv = *reinterpret_cast<const int4*>(state + (size_t)g * 256 + lane * 4);
    int c0 = cv.x, c1 = cv.y, c2 = cv.z, c3 = cv.w;

    const int a   = action[g];
    const int pp0 = pos_prev[2 * g],  pp1 = pos_prev[2 * g + 1];
    const int pc0 = pos_cur[2 * g],   pc1 = pos_cur[2 * g + 1];

    // Turn: action 0 = left, 1 = straight, 2 = right.
    const int d0 = pc0 - pp0, d1 = pc1 - pp1;
    int nd0 = d0, nd1 = d1;
    if (a == 0)      { nd0 = -d1; nd1 =  d0; }
    else if (a == 2) { nd0 =  d1; nd1 = -d0; }
    int pn0 = pc0 + nd0, pn1 = pc1 + nd1;
    const bool outside = (pn0 < 0) | (pn0 > 15) | (pn1 < 0) | (pn1 > 15);
    pn0 = min(max(pn0, 0), 15);
    pn1 = min(max(pn1, 0), 15);
    int flat_pn = pn0 * 16 + pn1;

    // Fetch a cell by flat index (wave-uniform index).
    auto cell_at = [&](int flat) -> int {
        const int e = flat & 3;
        const int mine = (e == 0) ? c0 : (e == 1) ? c1 : (e == 2) ? c2 : c3;
        return __shfl(mine, flat >> 2);
    };

    const int  cell    = cell_at(flat_pn);       // original state at pos_next
    const bool dead    = outside || (cell > 0);
    const bool feeding = (cell == -1);

    if (dead) {
        // Reset board; place snake 1,2,1 at (8,6),(8,7),(8,8) = flats 134,135,136.
        c0 = 0; c1 = 0; c2 = 0; c3 = 0;
        if (lane == 33) { c2 = 1; c3 = 2; }   // lane 33 owns flats 132..135
        if (lane == 34) { c0 = 1; }           // flat 136
        flat_pn = 136;                        // pos_next := (8,8)
    }
    const int flat_pc = dead ? 135 : (pc0 * 16 + pc1);  // pos_cur := (8,7) if dead

    // Food spawn (wave-uniform predicate): argmax over empty cells of rand_food.
    if (dead || feeding) {
        const float4 rv = *reinterpret_cast<const float4*>(rand_food + (size_t)g * 256 + lane * 4);
        float bv = (c0 == 0) ? rv.x : -1.0f;  int bi = lane * 4;
        const float v1 = (c1 == 0) ? rv.y : -1.0f;
        const float v2 = (c2 == 0) ? rv.z : -1.0f;
        const float v3 = (c3 == 0) ? rv.w : -1.0f;
        if (v1 > bv) { bv = v1; bi = lane * 4 + 1; }
        if (v2 > bv) { bv = v2; bi = lane * 4 + 2; }
        if (v3 > bv) { bv = v3; bi = lane * 4 + 3; }
        // Butterfly reduce: max value, ties -> lowest index (argmax semantics).
        for (int off = 32; off >= 1; off >>= 1) {
            const float ov = __shfl_xor(bv, off);
            const int   oi = __shfl_xor(bi, off);
            if (ov > bv || (ov == bv && oi < bi)) { bv = ov; bi = oi; }
        }
        if ((bi >> 2) == lane) {
            const int e = bi & 3;
            if      (e == 0) c0 = -1;
            else if (e == 1) c1 = -1;
            else if (e == 2) c2 = -1;
            else             c3 = -1;
        }
    }

    // Decrement snake cells unless feeding (snake grows).
    if (!feeding) {
        if (c0 > 0) --c0;
        if (c1 > 0) --c1;
        if (c2 > 0) --c2;
        if (c3 > 0) --c3;
    }

    // New head value = state[pos_cur] (post-decrement) + 1, written at pos_next.
    const int head = cell_at(flat_pc) + 1;
    if ((flat_pn >> 2) == lane) {
        const int e = flat_pn & 3;
        if      (e == 0) c0 = head;
        else if (e == 1) c1 = head;
        else if (e == 2) c2 = head;
        else             c3 = head;
    }

    int4 o;
    o.x = c0; o.y = c1; o.z = c2; o.w = c3;
    *reinterpret_cast<int4*>(out + (size_t)g * 256 + lane * 4) = o;
}

extern "C" void kernel_launch(void* const* d_in, const int* in_sizes, int n_in,
                              void* d_out, int out_size, void* d_ws, size_t ws_size,
                              hipStream_t stream) {
    const int*   action    = (const int*)d_in[0];
    const int*   pos_prev  = (const int*)d_in[1];
    const int*   pos_cur   = (const int*)d_in[2];
    const int*   state     = (const int*)d_in[3];
    const float* rand_food = (const float*)d_in[4];
    int*         out       = (int*)d_out;
    const int G = in_sizes[0];

    const int blocks = (G + 3) / 4;  // 4 waves (games) per 256-thread block
    snake_step<<<blocks, 256, 0, stream>>>(action, pos_prev, pos_cur, state,
                                           rand_food, out, G);
}